// Round 7
// baseline (892.917 us; speedup 1.0000x reference)
//
#include <hip/hip_runtime.h>

#define N_NODES 100000
#define N_EDGES 3200000
#define IN_DIM  512
#define HIDDEN  16
#define NCLS    7

#define BSH     7
#define BNODES  128                                  // nodes per bucket
#define NB      ((N_NODES + BNODES - 1) / BNODES)    // 782 buckets

#define EPB1    8192                                 // edges/block, k_bcount
#define NBLK1   ((N_EDGES + EPB1 - 1) / EPB1)        // 391
#define EPB2    4096                                 // edges/block, k_bscatter
#define NBLK2   ((N_EDGES + EPB2 - 1) / EPB2)        // 782

#define GEMM1_BLOCKS 512                             // 2048 waves = 8 waves/CU resident

// ---------------- init ----------------
__global__ void k_zero(int* __restrict__ bcnt) {
    bcnt[threadIdx.x] = 0;             // 1024 entries (>= NB)
}

// ---------------- coarse bucket histogram (per-block LDS, few global atomics) ----------------
__global__ __launch_bounds__(256) void k_bcount(const int* __restrict__ dst,
                                                int* __restrict__ bcnt) {
    __shared__ int hist[1024];
    int tid = threadIdx.x;
#pragma unroll
    for (int q = 0; q < 4; ++q) hist[q * 256 + tid] = 0;
    __syncthreads();
    int e0 = blockIdx.x * EPB1;
    int n  = min(EPB1, N_EDGES - e0);
    for (int k = tid; k < n; k += 256)
        atomicAdd(&hist[dst[e0 + k] >> BSH], 1);
    __syncthreads();
    for (int b = tid; b < NB; b += 256) {
        int c = hist[b];
        if (c) atomicAdd(&bcnt[b], c);
    }
}

// ---------------- scan NB bucket counts -> bstart, init global cursors ----------------
__global__ __launch_bounds__(256) void k_bscan(const int* __restrict__ bcnt,
                                               int* __restrict__ bstart,
                                               int* __restrict__ bcur) {
    __shared__ int ssum[256];
    int tid = threadIdx.x;
    int a[4];
#pragma unroll
    for (int k = 0; k < 4; ++k) {
        int idx = tid * 4 + k;
        a[k] = (idx < NB) ? bcnt[idx] : 0;
    }
    int s = a[0] + a[1] + a[2] + a[3];
    ssum[tid] = s;
    __syncthreads();
    for (int off = 1; off < 256; off <<= 1) {
        int t = (tid >= off) ? ssum[tid - off] : 0;
        __syncthreads();
        ssum[tid] += t;
        __syncthreads();
    }
    int run = ssum[tid] - s;           // exclusive prefix for this thread
#pragma unroll
    for (int k = 0; k < 4; ++k) {
        int idx = tid * 4 + k;
        if (idx < NB) { bstart[idx] = run; bcur[idx] = run; run += a[k]; }
    }
    if (tid == 0) bstart[NB] = N_EDGES;
}

// ---------------- bucket scatter: block reserves contiguous runs (coalesced writes) ----------
__global__ __launch_bounds__(256) void k_bscatter(const int* __restrict__ src,
                                                  const int* __restrict__ dst,
                                                  int* __restrict__ bcur,
                                                  unsigned int* __restrict__ ebuf) {
    __shared__ unsigned int pk[EPB2];
    __shared__ unsigned short bb[EPB2];
    __shared__ int hist[1024], base[1024], lcur[1024];
    int tid = threadIdx.x;
#pragma unroll
    for (int q = 0; q < 4; ++q) { hist[q * 256 + tid] = 0; lcur[q * 256 + tid] = 0; }
    __syncthreads();
    int e0 = blockIdx.x * EPB2;
    int n  = min(EPB2, N_EDGES - e0);
    for (int k = tid; k < n; k += 256) {
        int d = dst[e0 + k];
        int b = d >> BSH;
        pk[k] = ((unsigned int)src[e0 + k] << BSH) | (unsigned int)(d & (BNODES - 1));
        bb[k] = (unsigned short)b;
        atomicAdd(&hist[b], 1);
    }
    __syncthreads();
    for (int b = tid; b < NB; b += 256) {
        int h = hist[b];
        base[b] = h ? atomicAdd(&bcur[b], h) : 0;   // one global atomic per touched bucket
    }
    __syncthreads();
    for (int k = tid; k < n; k += 256) {
        int b = bb[k];
        int pos = atomicAdd(&lcur[b], 1);
        ebuf[base[b] + pos] = pk[k];                // block-private run -> L2 write-combine
    }
}

// ---------------- per-bucket degree histogram -> dinv ----------------
__global__ __launch_bounds__(256) void k_deginv(const int* __restrict__ bstart,
                                                const unsigned int* __restrict__ ebuf,
                                                float* __restrict__ dinv) {
    __shared__ int hist[BNODES];
    int tid = threadIdx.x;
    int b   = blockIdx.x;
    if (tid < BNODES) hist[tid] = 0;
    __syncthreads();
    int e0 = bstart[b], e1 = bstart[b + 1];
    for (int i = e0 + tid; i < e1; i += 256)
        atomicAdd(&hist[ebuf[i] & (BNODES - 1)], 1);
    __syncthreads();
    if (tid < BNODES) {
        int node = b * BNODES + tid;
        if (node < N_NODES) dinv[node] = rsqrtf((float)(hist[tid] + 1)); // +1 self-loop
    }
}

// ---------------- layer-1 GEMM: h1s = (x @ W1) * dinv ----------------
// One wave per node; W1 fragment in registers; value-halving butterfly reduction.
__global__ __launch_bounds__(256, 2) void k_gemm1(
    const float* __restrict__ x, const float* __restrict__ W1,
    const float* __restrict__ dinv, float* __restrict__ h1s) {
    const int tid = threadIdx.x;
    const int l   = tid & 63;
    const int wid = blockIdx.x * 4 + (tid >> 6);
    const int nw  = GEMM1_BLOCKS * 4;

    float w[8][16];
#pragma unroll
    for (int q = 0; q < 4; ++q) {
#pragma unroll
        for (int c = 0; c < 4; ++c) {
            float4 t0 = *(const float4*)(W1 + (size_t)(4 * l + q) * 16 + 4 * c);
            w[q][4*c+0] = t0.x; w[q][4*c+1] = t0.y; w[q][4*c+2] = t0.z; w[q][4*c+3] = t0.w;
            float4 t1 = *(const float4*)(W1 + (size_t)(256 + 4 * l + q) * 16 + 4 * c);
            w[4+q][4*c+0] = t1.x; w[4+q][4*c+1] = t1.y; w[4+q][4*c+2] = t1.z; w[4+q][4*c+3] = t1.w;
        }
    }

    const int b0 = l & 1, b1 = (l >> 1) & 1, b2 = (l >> 2) & 1, b3 = (l >> 3) & 1;

    int n = wid;
    if (n >= N_NODES) return;
    const float* xr = x + (size_t)n * IN_DIM;
    float4 v0 = *(const float4*)(xr + 4 * l);
    float4 v1 = *(const float4*)(xr + 256 + 4 * l);

    for (;;) {
        int n2 = n + nw;
        int np = (n2 < N_NODES) ? n2 : n;
        const float* xp = x + (size_t)np * IN_DIM;
        float4 u0 = *(const float4*)(xp + 4 * l);
        float4 u1 = *(const float4*)(xp + 256 + 4 * l);

        float p[16];
#pragma unroll
        for (int j = 0; j < 16; ++j) {
            float a = v0.x * w[0][j];
            a = fmaf(v0.y, w[1][j], a);
            a = fmaf(v0.z, w[2][j], a);
            a = fmaf(v0.w, w[3][j], a);
            a = fmaf(v1.x, w[4][j], a);
            a = fmaf(v1.y, w[5][j], a);
            a = fmaf(v1.z, w[6][j], a);
            a = fmaf(v1.w, w[7][j], a);
            p[j] = a;
        }

        float q8[8];
#pragma unroll
        for (int m = 0; m < 8; ++m) {
            float keep = b0 ? p[2*m+1] : p[2*m];
            float give = b0 ? p[2*m]   : p[2*m+1];
            q8[m] = keep + __shfl_xor(give, 1);
        }
        float r4[4];
#pragma unroll
        for (int t = 0; t < 4; ++t) {
            float keep = b1 ? q8[2*t+1] : q8[2*t];
            float give = b1 ? q8[2*t]   : q8[2*t+1];
            r4[t] = keep + __shfl_xor(give, 2);
        }
        float s2[2];
#pragma unroll
        for (int u = 0; u < 2; ++u) {
            float keep = b2 ? r4[2*u+1] : r4[2*u];
            float give = b2 ? r4[2*u]   : r4[2*u+1];
            s2[u] = keep + __shfl_xor(give, 4);
        }
        float t0 = (b3 ? s2[1] : s2[0]) + __shfl_xor(b3 ? s2[0] : s2[1], 8);
        t0 += __shfl_xor(t0, 16);
        t0 += __shfl_xor(t0, 32);

        float di = dinv[n];
        if (l < 16) h1s[(size_t)n * 16 + l] = t0 * di;

        n = n2;
        if (n >= N_NODES) break;
        v0 = u0; v1 = u1;
    }
}

// ---------------- bucket aggregate 1 + relu + layer-2 GEMM fused ----------------
// One block per bucket. 16-lane groups stream edges, LDS-atomic into acc[128][16].
// Epilogue: z = relu(dinv*(acc+self)+b1) in-place, then h2s = (z @ W2)*dinv.
__global__ __launch_bounds__(256) void k_bagg1(
    const int* __restrict__ bstart, const unsigned int* __restrict__ ebuf,
    const float* __restrict__ h1s, const float* __restrict__ dinv,
    const float* __restrict__ b1, const float* __restrict__ W2,
    float* __restrict__ h2s) {
    __shared__ float acc[BNODES * 16];   // 8 KB
    __shared__ float w2s[16 * 8];
    int tid = threadIdx.x;
    int b   = blockIdx.x;
#pragma unroll
    for (int q = 0; q < 8; ++q) acc[q * 256 + tid] = 0.f;
    if (tid < 128) {
        int k = tid >> 3, jj = tid & 7;
        w2s[tid] = (jj < 7) ? W2[k * 7 + jj] : 0.f;
    }
    __syncthreads();

    int e0 = bstart[b], e1 = bstart[b + 1];
    int g = tid >> 4, lane = tid & 15;   // 16 groups x 16 lanes
    for (int i = e0 + g; i < e1; i += 16) {
        unsigned int p = ebuf[i];        // same addr across group -> broadcast
        int s   = (int)(p >> BSH);
        int dlo = (int)(p & (BNODES - 1));
        float v = h1s[(size_t)s * 16 + lane];   // 64B per group
        atomicAdd(&acc[dlo * 16 + lane], v);
    }
    __syncthreads();

    // phase A: z = relu(dinv*(acc+self)+b1), in place
    for (int idx = tid; idx < BNODES * 16; idx += 256) {
        int dlo = idx >> 4, j = idx & 15;
        int node = b * BNODES + dlo;
        if (node < N_NODES) {
            float t = acc[idx] + h1s[(size_t)node * 16 + j];
            acc[idx] = fmaxf(dinv[node] * t + b1[j], 0.f);
        }
    }
    __syncthreads();

    // phase B: h2s = (z @ W2) * dinv, padded stride 8
    for (int idx = tid; idx < BNODES * 8; idx += 256) {
        int dlo = idx >> 3, jj = idx & 7;
        int node = b * BNODES + dlo;
        if (node < N_NODES) {
            float a = 0.f;
#pragma unroll
            for (int k = 0; k < 16; ++k) a = fmaf(acc[dlo * 16 + k], w2s[k * 8 + jj], a);
            h2s[(size_t)node * 8 + jj] = (jj < 7) ? a * dinv[node] : 0.f;
        }
    }
}

// ---------------- bucket aggregate 2 + bias + log_softmax fused ----------------
__global__ __launch_bounds__(256) void k_bagg2(
    const int* __restrict__ bstart, const unsigned int* __restrict__ ebuf,
    const float* __restrict__ h2s, const float* __restrict__ dinv,
    const float* __restrict__ b2, float* __restrict__ out) {
    __shared__ float acc[BNODES * 8];    // 4 KB
    int tid = threadIdx.x;
    int b   = blockIdx.x;
#pragma unroll
    for (int q = 0; q < 4; ++q) acc[q * 256 + tid] = 0.f;
    __syncthreads();

    int e0 = bstart[b], e1 = bstart[b + 1];
    int g = tid >> 3, lane = tid & 7;    // 32 groups x 8 lanes
    for (int i = e0 + g; i < e1; i += 32) {
        unsigned int p = ebuf[i];
        int s   = (int)(p >> BSH);
        int dlo = (int)(p & (BNODES - 1));
        atomicAdd(&acc[dlo * 8 + lane], h2s[(size_t)s * 8 + lane]);
    }
    __syncthreads();

    for (int dlo = g; dlo < BNODES; dlo += 32) {
        int node = b * BNODES + dlo;
        if (node >= N_NODES) continue;   // group-uniform
        float tot = acc[dlo * 8 + lane] + h2s[(size_t)node * 8 + lane];
        float v = dinv[node] * tot + ((lane < 7) ? b2[lane] : -1e30f);
        float m = v;
        m = fmaxf(m, __shfl_xor(m, 1));
        m = fmaxf(m, __shfl_xor(m, 2));
        m = fmaxf(m, __shfl_xor(m, 4));
        float e = (lane < 7) ? expf(v - m) : 0.f;
        float ssum = e;
        ssum += __shfl_xor(ssum, 1);
        ssum += __shfl_xor(ssum, 2);
        ssum += __shfl_xor(ssum, 4);
        float ls = logf(ssum) + m;
        if (lane < 7) out[(size_t)node * 7 + lane] = v - ls;
    }
}

extern "C" void kernel_launch(void* const* d_in, const int* in_sizes, int n_in,
                              void* d_out, int out_size, void* d_ws, size_t ws_size,
                              hipStream_t stream) {
    const float* x  = (const float*)d_in[0];
    const int*   ei = (const int*)d_in[1];
    const float* W1 = (const float*)d_in[2];
    const float* b1 = (const float*)d_in[3];
    const float* W2 = (const float*)d_in[4];
    const float* b2 = (const float*)d_in[5];
    float* out = (float*)d_out;

    const int* src = ei;             // edge_index[0]
    const int* dst = ei + N_EDGES;   // edge_index[1]

    char* ws = (char*)d_ws;
    size_t o = 0;
    auto alloc = [&](size_t bytes) -> void* {
        void* p = ws + o;
        o = (o + bytes + 255) & ~(size_t)255;
        return p;
    };
    int*   bcnt     = (int*)alloc(1024 * 4);
    int*   bstart   = (int*)alloc(1025 * 4);
    int*   bcur     = (int*)alloc(1024 * 4);
    float* dinv     = (float*)alloc((size_t)N_NODES * 4);
    unsigned int* ebuf = (unsigned int*)alloc((size_t)N_EDGES * 4);
    float* h1s      = (float*)alloc((size_t)N_NODES * 16 * 4);
    float* h2s      = (float*)alloc((size_t)N_NODES * 8 * 4);

    k_zero    <<<1, 1024, 0, stream>>>(bcnt);
    k_bcount  <<<NBLK1, 256, 0, stream>>>(dst, bcnt);
    k_bscan   <<<1, 256, 0, stream>>>(bcnt, bstart, bcur);
    k_bscatter<<<NBLK2, 256, 0, stream>>>(src, dst, bcur, ebuf);
    k_deginv  <<<NB, 256, 0, stream>>>(bstart, ebuf, dinv);
    k_gemm1   <<<GEMM1_BLOCKS, 256, 0, stream>>>(x, W1, dinv, h1s);
    k_bagg1   <<<NB, 256, 0, stream>>>(bstart, ebuf, h1s, dinv, b1, W2, h2s);
    k_bagg2   <<<NB, 256, 0, stream>>>(bstart, ebuf, h2s, dinv, b2, out);
}

// Round 8
// 888.845 us; speedup vs baseline: 1.0046x; 1.0046x over previous
//
#include <hip/hip_runtime.h>

#define N_NODES 100000
#define N_EDGES 3200000
#define IN_DIM  512
#define HIDDEN  16
#define NCLS    7

#define BSH     7
#define BNODES  128                                  // nodes per bucket
#define NB      ((N_NODES + BNODES - 1) / BNODES)    // 782 buckets

#define EPB1    8192                                 // edges/block, k_bcount
#define NBLK1   ((N_EDGES + EPB1 - 1) / EPB1)        // 391
#define EPB2    4096                                 // edges/block, k_bscatter
#define NBLK2   ((N_EDGES + EPB2 - 1) / EPB2)        // 782

#define GEMM1_BLOCKS 512                             // 2048 waves = 8 waves/CU resident

#define AGG_THREADS 512
#define NGRP1   (AGG_THREADS / 16)                   // 32 groups of 16 lanes
#define NGRP2   (AGG_THREADS / 8)                    // 64 groups of 8 lanes
#define UB      8                                    // edges batched per group iter

// ---------------- init ----------------
__global__ void k_zero(int* __restrict__ bcnt) {
    bcnt[threadIdx.x] = 0;             // 1024 entries (>= NB)
}

// ---------------- coarse bucket histogram (per-block LDS, few global atomics) ----------------
__global__ __launch_bounds__(256) void k_bcount(const int* __restrict__ dst,
                                                int* __restrict__ bcnt) {
    __shared__ int hist[1024];
    int tid = threadIdx.x;
#pragma unroll
    for (int q = 0; q < 4; ++q) hist[q * 256 + tid] = 0;
    __syncthreads();
    int e0 = blockIdx.x * EPB1;
    int n  = min(EPB1, N_EDGES - e0);
    for (int k = tid; k < n; k += 256)
        atomicAdd(&hist[dst[e0 + k] >> BSH], 1);
    __syncthreads();
    for (int b = tid; b < NB; b += 256) {
        int c = hist[b];
        if (c) atomicAdd(&bcnt[b], c);
    }
}

// ---------------- scan NB bucket counts -> bstart, init global cursors ----------------
__global__ __launch_bounds__(256) void k_bscan(const int* __restrict__ bcnt,
                                               int* __restrict__ bstart,
                                               int* __restrict__ bcur) {
    __shared__ int ssum[256];
    int tid = threadIdx.x;
    int a[4];
#pragma unroll
    for (int k = 0; k < 4; ++k) {
        int idx = tid * 4 + k;
        a[k] = (idx < NB) ? bcnt[idx] : 0;
    }
    int s = a[0] + a[1] + a[2] + a[3];
    ssum[tid] = s;
    __syncthreads();
    for (int off = 1; off < 256; off <<= 1) {
        int t = (tid >= off) ? ssum[tid - off] : 0;
        __syncthreads();
        ssum[tid] += t;
        __syncthreads();
    }
    int run = ssum[tid] - s;           // exclusive prefix for this thread
#pragma unroll
    for (int k = 0; k < 4; ++k) {
        int idx = tid * 4 + k;
        if (idx < NB) { bstart[idx] = run; bcur[idx] = run; run += a[k]; }
    }
    if (tid == 0) bstart[NB] = N_EDGES;
}

// ---------------- bucket scatter: block reserves contiguous runs (coalesced writes) ----------
__global__ __launch_bounds__(256) void k_bscatter(const int* __restrict__ src,
                                                  const int* __restrict__ dst,
                                                  int* __restrict__ bcur,
                                                  unsigned int* __restrict__ ebuf) {
    __shared__ unsigned int pk[EPB2];
    __shared__ unsigned short bb[EPB2];
    __shared__ int hist[1024], base[1024], lcur[1024];
    int tid = threadIdx.x;
#pragma unroll
    for (int q = 0; q < 4; ++q) { hist[q * 256 + tid] = 0; lcur[q * 256 + tid] = 0; }
    __syncthreads();
    int e0 = blockIdx.x * EPB2;
    int n  = min(EPB2, N_EDGES - e0);
    for (int k = tid; k < n; k += 256) {
        int d = dst[e0 + k];
        int b = d >> BSH;
        pk[k] = ((unsigned int)src[e0 + k] << BSH) | (unsigned int)(d & (BNODES - 1));
        bb[k] = (unsigned short)b;
        atomicAdd(&hist[b], 1);
    }
    __syncthreads();
    for (int b = tid; b < NB; b += 256) {
        int h = hist[b];
        base[b] = h ? atomicAdd(&bcur[b], h) : 0;   // one global atomic per touched bucket
    }
    __syncthreads();
    for (int k = tid; k < n; k += 256) {
        int b = bb[k];
        int pos = atomicAdd(&lcur[b], 1);
        ebuf[base[b] + pos] = pk[k];                // block-private run -> L2 write-combine
    }
}

// ---------------- per-bucket degree histogram -> dinv ----------------
__global__ __launch_bounds__(256) void k_deginv(const int* __restrict__ bstart,
                                                const unsigned int* __restrict__ ebuf,
                                                float* __restrict__ dinv) {
    __shared__ int hist[BNODES];
    int tid = threadIdx.x;
    int b   = blockIdx.x;
    if (tid < BNODES) hist[tid] = 0;
    __syncthreads();
    int e0 = bstart[b], e1 = bstart[b + 1];
    for (int i = e0 + tid; i < e1; i += 256)
        atomicAdd(&hist[ebuf[i] & (BNODES - 1)], 1);
    __syncthreads();
    if (tid < BNODES) {
        int node = b * BNODES + tid;
        if (node < N_NODES) dinv[node] = rsqrtf((float)(hist[tid] + 1)); // +1 self-loop
    }
}

// ---------------- layer-1 GEMM: h1s = (x @ W1) * dinv ----------------
// One wave per node; W1 fragment in registers; value-halving butterfly reduction.
__global__ __launch_bounds__(256, 2) void k_gemm1(
    const float* __restrict__ x, const float* __restrict__ W1,
    const float* __restrict__ dinv, float* __restrict__ h1s) {
    const int tid = threadIdx.x;
    const int l   = tid & 63;
    const int wid = blockIdx.x * 4 + (tid >> 6);
    const int nw  = GEMM1_BLOCKS * 4;

    float w[8][16];
#pragma unroll
    for (int q = 0; q < 4; ++q) {
#pragma unroll
        for (int c = 0; c < 4; ++c) {
            float4 t0 = *(const float4*)(W1 + (size_t)(4 * l + q) * 16 + 4 * c);
            w[q][4*c+0] = t0.x; w[q][4*c+1] = t0.y; w[q][4*c+2] = t0.z; w[q][4*c+3] = t0.w;
            float4 t1 = *(const float4*)(W1 + (size_t)(256 + 4 * l + q) * 16 + 4 * c);
            w[4+q][4*c+0] = t1.x; w[4+q][4*c+1] = t1.y; w[4+q][4*c+2] = t1.z; w[4+q][4*c+3] = t1.w;
        }
    }

    const int b0 = l & 1, b1 = (l >> 1) & 1, b2 = (l >> 2) & 1, b3 = (l >> 3) & 1;

    int n = wid;
    if (n >= N_NODES) return;
    const float* xr = x + (size_t)n * IN_DIM;
    float4 v0 = *(const float4*)(xr + 4 * l);
    float4 v1 = *(const float4*)(xr + 256 + 4 * l);

    for (;;) {
        int n2 = n + nw;
        int np = (n2 < N_NODES) ? n2 : n;
        const float* xp = x + (size_t)np * IN_DIM;
        float4 u0 = *(const float4*)(xp + 4 * l);
        float4 u1 = *(const float4*)(xp + 256 + 4 * l);

        float p[16];
#pragma unroll
        for (int j = 0; j < 16; ++j) {
            float a = v0.x * w[0][j];
            a = fmaf(v0.y, w[1][j], a);
            a = fmaf(v0.z, w[2][j], a);
            a = fmaf(v0.w, w[3][j], a);
            a = fmaf(v1.x, w[4][j], a);
            a = fmaf(v1.y, w[5][j], a);
            a = fmaf(v1.z, w[6][j], a);
            a = fmaf(v1.w, w[7][j], a);
            p[j] = a;
        }

        float q8[8];
#pragma unroll
        for (int m = 0; m < 8; ++m) {
            float keep = b0 ? p[2*m+1] : p[2*m];
            float give = b0 ? p[2*m]   : p[2*m+1];
            q8[m] = keep + __shfl_xor(give, 1);
        }
        float r4[4];
#pragma unroll
        for (int t = 0; t < 4; ++t) {
            float keep = b1 ? q8[2*t+1] : q8[2*t];
            float give = b1 ? q8[2*t]   : q8[2*t+1];
            r4[t] = keep + __shfl_xor(give, 2);
        }
        float s2[2];
#pragma unroll
        for (int u = 0; u < 2; ++u) {
            float keep = b2 ? r4[2*u+1] : r4[2*u];
            float give = b2 ? r4[2*u]   : r4[2*u+1];
            s2[u] = keep + __shfl_xor(give, 4);
        }
        float t0 = (b3 ? s2[1] : s2[0]) + __shfl_xor(b3 ? s2[0] : s2[1], 8);
        t0 += __shfl_xor(t0, 16);
        t0 += __shfl_xor(t0, 32);

        float di = dinv[n];
        if (l < 16) h1s[(size_t)n * 16 + l] = t0 * di;

        n = n2;
        if (n >= N_NODES) break;
        v0 = u0; v1 = u1;
    }
}

// ---------------- bucket aggregate 1 + relu + layer-2 GEMM fused ----------------
// One block (512 thr) per bucket. 16-lane groups batch UB=8 edges: 8 independent
// 64B gathers in flight per group before LDS atomics -> MLP, not latency chain.
__global__ __launch_bounds__(AGG_THREADS) void k_bagg1(
    const int* __restrict__ bstart, const unsigned int* __restrict__ ebuf,
    const float* __restrict__ h1s, const float* __restrict__ dinv,
    const float* __restrict__ b1, const float* __restrict__ W2,
    float* __restrict__ h2s) {
    __shared__ float acc[BNODES * 16];   // 8 KB
    __shared__ float w2s[16 * 8];
    int tid = threadIdx.x;
    int b   = blockIdx.x;
#pragma unroll
    for (int q = 0; q < 4; ++q) acc[q * AGG_THREADS + tid] = 0.f;
    if (tid < 128) {
        int k = tid >> 3, jj = tid & 7;
        w2s[tid] = (jj < 7) ? W2[k * 7 + jj] : 0.f;
    }
    __syncthreads();

    int e0 = bstart[b], e1 = bstart[b + 1];
    int g = tid >> 4, lane = tid & 15;   // 32 groups x 16 lanes
    for (int base = e0 + g * UB; base < e1; base += NGRP1 * UB) {
        int cnt = min(UB, e1 - base);
        unsigned int p[UB];
#pragma unroll
        for (int u = 0; u < UB; ++u)
            p[u] = (u < cnt) ? ebuf[base + u] : 0u;
        float v[UB];
        int dl[UB];
#pragma unroll
        for (int u = 0; u < UB; ++u) {
            int s = (int)(p[u] >> BSH);
            dl[u] = (int)(p[u] & (BNODES - 1));
            v[u]  = (u < cnt) ? h1s[(size_t)s * 16 + lane] : 0.f;  // 8 gathers in flight
        }
#pragma unroll
        for (int u = 0; u < UB; ++u)
            if (u < cnt) atomicAdd(&acc[dl[u] * 16 + lane], v[u]);
    }
    __syncthreads();

    // phase A: z = relu(dinv*(acc+self)+b1), in place
    for (int idx = tid; idx < BNODES * 16; idx += AGG_THREADS) {
        int dlo = idx >> 4, j = idx & 15;
        int node = b * BNODES + dlo;
        if (node < N_NODES) {
            float t = acc[idx] + h1s[(size_t)node * 16 + j];
            acc[idx] = fmaxf(dinv[node] * t + b1[j], 0.f);
        }
    }
    __syncthreads();

    // phase B: h2s = (z @ W2) * dinv, padded stride 8
    for (int idx = tid; idx < BNODES * 8; idx += AGG_THREADS) {
        int dlo = idx >> 3, jj = idx & 7;
        int node = b * BNODES + dlo;
        if (node < N_NODES) {
            float a = 0.f;
#pragma unroll
            for (int k = 0; k < 16; ++k) a = fmaf(acc[dlo * 16 + k], w2s[k * 8 + jj], a);
            h2s[(size_t)node * 8 + jj] = (jj < 7) ? a * dinv[node] : 0.f;
        }
    }
}

// ---------------- bucket aggregate 2 + bias + log_softmax fused ----------------
__global__ __launch_bounds__(AGG_THREADS) void k_bagg2(
    const int* __restrict__ bstart, const unsigned int* __restrict__ ebuf,
    const float* __restrict__ h2s, const float* __restrict__ dinv,
    const float* __restrict__ b2, float* __restrict__ out) {
    __shared__ float acc[BNODES * 8];    // 4 KB
    int tid = threadIdx.x;
    int b   = blockIdx.x;
#pragma unroll
    for (int q = 0; q < 2; ++q) acc[q * AGG_THREADS + tid] = 0.f;
    __syncthreads();

    int e0 = bstart[b], e1 = bstart[b + 1];
    int g = tid >> 3, lane = tid & 7;    // 64 groups x 8 lanes
    for (int base = e0 + g * UB; base < e1; base += NGRP2 * UB) {
        int cnt = min(UB, e1 - base);
        unsigned int p[UB];
#pragma unroll
        for (int u = 0; u < UB; ++u)
            p[u] = (u < cnt) ? ebuf[base + u] : 0u;
        float v[UB];
        int dl[UB];
#pragma unroll
        for (int u = 0; u < UB; ++u) {
            int s = (int)(p[u] >> BSH);
            dl[u] = (int)(p[u] & (BNODES - 1));
            v[u]  = (u < cnt) ? h2s[(size_t)s * 8 + lane] : 0.f;   // 8 gathers in flight
        }
#pragma unroll
        for (int u = 0; u < UB; ++u)
            if (u < cnt) atomicAdd(&acc[dl[u] * 8 + lane], v[u]);
    }
    __syncthreads();

    for (int dlo = g; dlo < BNODES; dlo += NGRP2) {
        int node = b * BNODES + dlo;
        if (node >= N_NODES) continue;   // group-uniform
        float tot = acc[dlo * 8 + lane] + h2s[(size_t)node * 8 + lane];
        float v = dinv[node] * tot + ((lane < 7) ? b2[lane] : -1e30f);
        float m = v;
        m = fmaxf(m, __shfl_xor(m, 1));
        m = fmaxf(m, __shfl_xor(m, 2));
        m = fmaxf(m, __shfl_xor(m, 4));
        float e = (lane < 7) ? expf(v - m) : 0.f;
        float ssum = e;
        ssum += __shfl_xor(ssum, 1);
        ssum += __shfl_xor(ssum, 2);
        ssum += __shfl_xor(ssum, 4);
        float ls = logf(ssum) + m;
        if (lane < 7) out[(size_t)node * 7 + lane] = v - ls;
    }
}

extern "C" void kernel_launch(void* const* d_in, const int* in_sizes, int n_in,
                              void* d_out, int out_size, void* d_ws, size_t ws_size,
                              hipStream_t stream) {
    const float* x  = (const float*)d_in[0];
    const int*   ei = (const int*)d_in[1];
    const float* W1 = (const float*)d_in[2];
    const float* b1 = (const float*)d_in[3];
    const float* W2 = (const float*)d_in[4];
    const float* b2 = (const float*)d_in[5];
    float* out = (float*)d_out;

    const int* src = ei;             // edge_index[0]
    const int* dst = ei + N_EDGES;   // edge_index[1]

    char* ws = (char*)d_ws;
    size_t o = 0;
    auto alloc = [&](size_t bytes) -> void* {
        void* p = ws + o;
        o = (o + bytes + 255) & ~(size_t)255;
        return p;
    };
    int*   bcnt     = (int*)alloc(1024 * 4);
    int*   bstart   = (int*)alloc(1025 * 4);
    int*   bcur     = (int*)alloc(1024 * 4);
    float* dinv     = (float*)alloc((size_t)N_NODES * 4);
    unsigned int* ebuf = (unsigned int*)alloc((size_t)N_EDGES * 4);
    float* h1s      = (float*)alloc((size_t)N_NODES * 16 * 4);
    float* h2s      = (float*)alloc((size_t)N_NODES * 8 * 4);

    k_zero    <<<1, 1024, 0, stream>>>(bcnt);
    k_bcount  <<<NBLK1, 256, 0, stream>>>(dst, bcnt);
    k_bscan   <<<1, 256, 0, stream>>>(bcnt, bstart, bcur);
    k_bscatter<<<NBLK2, 256, 0, stream>>>(src, dst, bcur, ebuf);
    k_deginv  <<<NB, 256, 0, stream>>>(bstart, ebuf, dinv);
    k_gemm1   <<<GEMM1_BLOCKS, 256, 0, stream>>>(x, W1, dinv, h1s);
    k_bagg1   <<<NB, AGG_THREADS, 0, stream>>>(bstart, ebuf, h1s, dinv, b1, W2, h2s);
    k_bagg2   <<<NB, AGG_THREADS, 0, stream>>>(bstart, ebuf, h2s, dinv, b2, out);
}

// Round 9
// 462.304 us; speedup vs baseline: 1.9315x; 1.9226x over previous
//
#include <hip/hip_runtime.h>

#define N_NODES 100000
#define N_EDGES 3200000
#define IN_DIM  512
#define HIDDEN  16
#define NCLS    7

#define BSH     9
#define BNODES  512                                  // nodes per bucket
#define NB      ((N_NODES + BNODES - 1) / BNODES)    // 196 buckets

#define EPB1    8192                                 // edges/block, k_bcount
#define NBLK1   ((N_EDGES + EPB1 - 1) / EPB1)        // 391
#define EPB2    4096                                 // edges/block, k_bscatter
#define NBLK2   ((N_EDGES + EPB2 - 1) / EPB2)        // 782

#define GEMM1_BLOCKS 512                             // 2048 waves

// ---------------- init ----------------
__global__ void k_zero(int* __restrict__ bcnt, int* __restrict__ rowstart) {
    int i = threadIdx.x;
    bcnt[i] = 0;                       // 256 entries (>= NB)
    if (i == 0) rowstart[N_NODES] = N_EDGES;
}

// ---------------- coarse bucket histogram (per-block LDS, few global atomics) ----------------
__global__ __launch_bounds__(256) void k_bcount(const int* __restrict__ dst,
                                                int* __restrict__ bcnt) {
    __shared__ int hist[256];
    int tid = threadIdx.x;
    hist[tid] = 0;
    __syncthreads();
    int e0 = blockIdx.x * EPB1;
    int n  = min(EPB1, N_EDGES - e0);
    for (int k = tid; k < n; k += 256)
        atomicAdd(&hist[dst[e0 + k] >> BSH], 1);
    __syncthreads();
    int c = hist[tid];
    if (c) atomicAdd(&bcnt[tid], c);
}

// ---------------- scan 196 bucket counts -> bstart, init global cursors ----------------
__global__ __launch_bounds__(256) void k_bscan(const int* __restrict__ bcnt,
                                               int* __restrict__ bstart,
                                               int* __restrict__ bcur) {
    __shared__ int s[256];
    int tid = threadIdx.x;
    int c = bcnt[tid];
    s[tid] = c;
    __syncthreads();
    for (int off = 1; off < 256; off <<= 1) {
        int t = (tid >= off) ? s[tid - off] : 0;
        __syncthreads();
        s[tid] += t;
        __syncthreads();
    }
    if (tid == 0) bstart[0] = 0;
    bstart[tid + 1] = s[tid];          // inclusive -> bstart[b+1]
    bcur[tid]       = s[tid] - c;      // exclusive base, running cursor
}

// ---------------- bucket scatter: block reserves contiguous runs (coalesced writes) ----------
__global__ __launch_bounds__(256) void k_bscatter(const int* __restrict__ src,
                                                  const int* __restrict__ dst,
                                                  int* __restrict__ bcur,
                                                  unsigned int* __restrict__ ebuf) {
    __shared__ unsigned int pk[EPB2];
    __shared__ unsigned short bb[EPB2];
    __shared__ int hist[256], base[256], lcur[256];
    int tid = threadIdx.x;
    hist[tid] = 0; lcur[tid] = 0;
    __syncthreads();
    int e0 = blockIdx.x * EPB2;
    int n  = min(EPB2, N_EDGES - e0);
    for (int k = tid; k < n; k += 256) {
        int d = dst[e0 + k];
        int b = d >> BSH;
        pk[k] = ((unsigned int)src[e0 + k] << BSH) | (unsigned int)(d & (BNODES - 1));
        bb[k] = (unsigned short)b;
        atomicAdd(&hist[b], 1);
    }
    __syncthreads();
    int h = hist[tid];
    base[tid] = h ? atomicAdd(&bcur[tid], h) : 0;   // one global atomic per touched bucket
    __syncthreads();
    for (int k = tid; k < n; k += 256) {
        int b = bb[k];
        int pos = atomicAdd(&lcur[b], 1);
        ebuf[base[b] + pos] = pk[k];                // block-private run -> L2 write-combine
    }
}

// ---------------- per-bucket LDS counting sort: csr_src + rowstart + dinv ----------------
__global__ __launch_bounds__(512) void k_bsort(const int* __restrict__ bstart,
                                               const unsigned int* __restrict__ ebuf,
                                               int* __restrict__ rowstart,
                                               float* __restrict__ dinv,
                                               int* __restrict__ csr_src) {
    __shared__ int hist[512], cur[512];
    int tid = threadIdx.x;
    int b   = blockIdx.x;
    int e0 = bstart[b], e1 = bstart[b + 1];
    hist[tid] = 0;
    __syncthreads();
    for (int i = e0 + tid; i < e1; i += 512)
        atomicAdd(&hist[ebuf[i] & (BNODES - 1)], 1);
    __syncthreads();
    int deg = hist[tid];
    for (int off = 1; off < 512; off <<= 1) {       // inclusive Hillis-Steele
        int t = (tid >= off) ? hist[tid - off] : 0;
        __syncthreads();
        hist[tid] += t;
        __syncthreads();
    }
    int excl = hist[tid] - deg;
    int node = (b << BSH) + tid;
    if (node < N_NODES) {
        rowstart[node] = e0 + excl;
        dinv[node]     = rsqrtf((float)(deg + 1)); // +1 self-loop
    }
    cur[tid] = excl;
    __syncthreads();
    for (int i = e0 + tid; i < e1; i += 512) {
        unsigned int p = ebuf[i];
        int pos = atomicAdd(&cur[p & (BNODES - 1)], 1);
        csr_src[e0 + pos] = (int)(p >> BSH);        // block-private region
    }
}

// ---------------- layer-1 GEMM: h1s = (x @ W1) * dinv ----------------
// One wave per node; W1 fragment in registers; value-halving butterfly reduction.
__global__ __launch_bounds__(256, 2) void k_gemm1(
    const float* __restrict__ x, const float* __restrict__ W1,
    const float* __restrict__ dinv, float* __restrict__ h1s) {
    const int tid = threadIdx.x;
    const int l   = tid & 63;
    const int wid = blockIdx.x * 4 + (tid >> 6);
    const int nw  = GEMM1_BLOCKS * 4;

    float w[8][16];
#pragma unroll
    for (int q = 0; q < 4; ++q) {
#pragma unroll
        for (int c = 0; c < 4; ++c) {
            float4 t0 = *(const float4*)(W1 + (size_t)(4 * l + q) * 16 + 4 * c);
            w[q][4*c+0] = t0.x; w[q][4*c+1] = t0.y; w[q][4*c+2] = t0.z; w[q][4*c+3] = t0.w;
            float4 t1 = *(const float4*)(W1 + (size_t)(256 + 4 * l + q) * 16 + 4 * c);
            w[4+q][4*c+0] = t1.x; w[4+q][4*c+1] = t1.y; w[4+q][4*c+2] = t1.z; w[4+q][4*c+3] = t1.w;
        }
    }

    const int b0 = l & 1, b1 = (l >> 1) & 1, b2 = (l >> 2) & 1, b3 = (l >> 3) & 1;

    int n = wid;
    if (n >= N_NODES) return;
    const float* xr = x + (size_t)n * IN_DIM;
    float4 v0 = *(const float4*)(xr + 4 * l);
    float4 v1 = *(const float4*)(xr + 256 + 4 * l);

    for (;;) {
        int n2 = n + nw;
        int np = (n2 < N_NODES) ? n2 : n;
        const float* xp = x + (size_t)np * IN_DIM;
        float4 u0 = *(const float4*)(xp + 4 * l);
        float4 u1 = *(const float4*)(xp + 256 + 4 * l);

        float p[16];
#pragma unroll
        for (int j = 0; j < 16; ++j) {
            float a = v0.x * w[0][j];
            a = fmaf(v0.y, w[1][j], a);
            a = fmaf(v0.z, w[2][j], a);
            a = fmaf(v0.w, w[3][j], a);
            a = fmaf(v1.x, w[4][j], a);
            a = fmaf(v1.y, w[5][j], a);
            a = fmaf(v1.z, w[6][j], a);
            a = fmaf(v1.w, w[7][j], a);
            p[j] = a;
        }

        float q8[8];
#pragma unroll
        for (int m = 0; m < 8; ++m) {
            float keep = b0 ? p[2*m+1] : p[2*m];
            float give = b0 ? p[2*m]   : p[2*m+1];
            q8[m] = keep + __shfl_xor(give, 1);
        }
        float r4[4];
#pragma unroll
        for (int t = 0; t < 4; ++t) {
            float keep = b1 ? q8[2*t+1] : q8[2*t];
            float give = b1 ? q8[2*t]   : q8[2*t+1];
            r4[t] = keep + __shfl_xor(give, 2);
        }
        float s2[2];
#pragma unroll
        for (int u = 0; u < 2; ++u) {
            float keep = b2 ? r4[2*u+1] : r4[2*u];
            float give = b2 ? r4[2*u]   : r4[2*u+1];
            s2[u] = keep + __shfl_xor(give, 4);
        }
        float t0 = (b3 ? s2[1] : s2[0]) + __shfl_xor(b3 ? s2[0] : s2[1], 8);
        t0 += __shfl_xor(t0, 16);
        t0 += __shfl_xor(t0, 32);

        float di = dinv[n];
        if (l < 16) h1s[(size_t)n * 16 + l] = t0 * di;

        n = n2;
        if (n >= N_NODES) break;
        v0 = u0; v1 = u1;
    }
}

// ---------------- layer-1 gather-aggregate + bias + relu ----------------
// 16 threads per node; register accumulate; explicit 8-edge batches for MLP.
__global__ __launch_bounds__(256) void k_agg1(
    const int* __restrict__ rowstart, const int* __restrict__ csr_src,
    const float* __restrict__ h1s, const float* __restrict__ dinv,
    const float* __restrict__ b1, float* __restrict__ z) {
    int gid = blockIdx.x * 256 + threadIdx.x;
    int g = gid >> 4, j = gid & 15;
    bool valid = g < N_NODES;
    int n = valid ? g : (N_NODES - 1);
    int start = rowstart[n], end = rowstart[n + 1];
    float acc = h1s[(size_t)n * 16 + j];   // self-loop term
    int i = start;
    for (; i + 8 <= end; i += 8) {
        int s[8];
#pragma unroll
        for (int u = 0; u < 8; ++u) s[u] = csr_src[i + u];
        float v[8];
#pragma unroll
        for (int u = 0; u < 8; ++u) v[u] = h1s[(size_t)s[u] * 16 + j];  // 8 gathers in flight
        acc += ((v[0] + v[1]) + (v[2] + v[3])) + ((v[4] + v[5]) + (v[6] + v[7]));
    }
    for (; i < end; ++i)
        acc += h1s[(size_t)csr_src[i] * 16 + j];
    if (valid) {
        float v = dinv[n] * acc + b1[j];
        z[(size_t)n * 16 + j] = fmaxf(v, 0.f);
    }
}

// ---------------- layer-2 GEMM: h2s = (z @ W2) * dinv, padded stride 8 ----------------
__global__ __launch_bounds__(256) void k_layer2(
    const float* __restrict__ z, const float* __restrict__ W2,
    const float* __restrict__ dinv, float* __restrict__ h2s) {
    int n = blockIdx.x * 256 + threadIdx.x;
    if (n >= N_NODES) return;
    float zv[16];
#pragma unroll
    for (int k = 0; k < 16; k += 4) {
        float4 v = *(const float4*)(z + (size_t)n * 16 + k);
        zv[k] = v.x; zv[k+1] = v.y; zv[k+2] = v.z; zv[k+3] = v.w;
    }
    float di = dinv[n];
    float o[8];
#pragma unroll
    for (int jj = 0; jj < 7; ++jj) {
        float a = 0.f;
#pragma unroll
        for (int k = 0; k < 16; ++k) a = fmaf(zv[k], W2[k * 7 + jj], a);
        o[jj] = a * di;
    }
    o[7] = 0.f;
    *(float4*)(h2s + (size_t)n * 8 + 0) = make_float4(o[0], o[1], o[2], o[3]);
    *(float4*)(h2s + (size_t)n * 8 + 4) = make_float4(o[4], o[5], o[6], o[7]);
}

// ---------------- layer-2 gather-aggregate + bias + log_softmax ----------------
// 8 threads per node; register accumulate; explicit 8-edge batches for MLP.
__global__ __launch_bounds__(256) void k_agg2(
    const int* __restrict__ rowstart, const int* __restrict__ csr_src,
    const float* __restrict__ h2s, const float* __restrict__ dinv,
    const float* __restrict__ b2, float* __restrict__ out) {
    int gid = blockIdx.x * 256 + threadIdx.x;
    int g = gid >> 3, j = gid & 7;
    bool valid = g < N_NODES;
    int n = valid ? g : (N_NODES - 1);
    int start = rowstart[n], end = rowstart[n + 1];
    float acc = h2s[(size_t)n * 8 + j];    // self-loop term (slot 7 reads 0)
    int i = start;
    for (; i + 8 <= end; i += 8) {
        int s[8];
#pragma unroll
        for (int u = 0; u < 8; ++u) s[u] = csr_src[i + u];
        float v[8];
#pragma unroll
        for (int u = 0; u < 8; ++u) v[u] = h2s[(size_t)s[u] * 8 + j];   // 8 gathers in flight
        acc += ((v[0] + v[1]) + (v[2] + v[3])) + ((v[4] + v[5]) + (v[6] + v[7]));
    }
    for (; i < end; ++i)
        acc += h2s[(size_t)csr_src[i] * 8 + j];
    float v = dinv[n] * acc + ((j < 7) ? b2[j] : -1e30f);
    float m = v;
    m = fmaxf(m, __shfl_xor(m, 1));
    m = fmaxf(m, __shfl_xor(m, 2));
    m = fmaxf(m, __shfl_xor(m, 4));
    float e = (j < 7) ? expf(v - m) : 0.f;
    float ssum = e;
    ssum += __shfl_xor(ssum, 1);
    ssum += __shfl_xor(ssum, 2);
    ssum += __shfl_xor(ssum, 4);
    float ls = logf(ssum) + m;
    if (valid && j < 7) out[(size_t)n * 7 + j] = v - ls;
}

extern "C" void kernel_launch(void* const* d_in, const int* in_sizes, int n_in,
                              void* d_out, int out_size, void* d_ws, size_t ws_size,
                              hipStream_t stream) {
    const float* x  = (const float*)d_in[0];
    const int*   ei = (const int*)d_in[1];
    const float* W1 = (const float*)d_in[2];
    const float* b1 = (const float*)d_in[3];
    const float* W2 = (const float*)d_in[4];
    const float* b2 = (const float*)d_in[5];
    float* out = (float*)d_out;

    const int* src = ei;             // edge_index[0]
    const int* dst = ei + N_EDGES;   // edge_index[1]

    char* ws = (char*)d_ws;
    size_t o = 0;
    auto alloc = [&](size_t bytes) -> void* {
        void* p = ws + o;
        o = (o + bytes + 255) & ~(size_t)255;
        return p;
    };
    int*   bcnt     = (int*)alloc(256 * 4);
    int*   bstart   = (int*)alloc(257 * 4);
    int*   bcur     = (int*)alloc(256 * 4);
    int*   rowstart = (int*)alloc(((size_t)N_NODES + 1) * 4);
    float* dinv     = (float*)alloc((size_t)N_NODES * 4);
    int*   csr_src  = (int*)alloc((size_t)N_EDGES * 4);
    // union: ebuf (dead after k_bsort) overlaps h1s+z (live after k_bsort)
    char*  uni      = (char*)alloc((size_t)N_EDGES * 4);   // 12.8MB = 16N*4 + 16N*4
    unsigned int* ebuf = (unsigned int*)uni;
    float* h1s      = (float*)uni;
    float* z        = h1s + (size_t)N_NODES * 16;
    float* h2s      = (float*)alloc((size_t)N_NODES * 8 * 4);

    const int nb_n = (N_NODES + 255) / 256;

    k_zero    <<<1, 256, 0, stream>>>(bcnt, rowstart);
    k_bcount  <<<NBLK1, 256, 0, stream>>>(dst, bcnt);
    k_bscan   <<<1, 256, 0, stream>>>(bcnt, bstart, bcur);
    k_bscatter<<<NBLK2, 256, 0, stream>>>(src, dst, bcur, ebuf);
    k_bsort   <<<NB, 512, 0, stream>>>(bstart, ebuf, rowstart, dinv, csr_src);
    k_gemm1   <<<GEMM1_BLOCKS, 256, 0, stream>>>(x, W1, dinv, h1s);
    k_agg1    <<<(N_NODES * 16 + 255) / 256, 256, 0, stream>>>(rowstart, csr_src, h1s, dinv, b1, z);
    k_layer2  <<<nb_n, 256, 0, stream>>>(z, W2, dinv, h2s);
    k_agg2    <<<(N_NODES * 8 + 255) / 256, 256, 0, stream>>>(rowstart, csr_src, h2s, dinv, b2, out);
}

// Round 10
// 456.640 us; speedup vs baseline: 1.9554x; 1.0124x over previous
//
#include <hip/hip_runtime.h>

#define N_NODES 100000
#define N_EDGES 3200000
#define IN_DIM  512
#define HIDDEN  16
#define NCLS    7

#define BSH     9
#define BNODES  512                                  // nodes per bucket
#define NB      ((N_NODES + BNODES - 1) / BNODES)    // 196 buckets

#define EPB1    8192                                 // edges/block, k_bcount
#define NBLK1   ((N_EDGES + EPB1 - 1) / EPB1)        // 391
#define EPB2    4096                                 // edges/block, k_bscatter
#define NBLK2   ((N_EDGES + EPB2 - 1) / EPB2)        // 782

#define GEMM1_BLOCKS 512                             // 2048 waves = 2/SIMD full residency

// ---------------- init ----------------
__global__ void k_zero(int* __restrict__ bcnt, int* __restrict__ rowstart) {
    int i = threadIdx.x;
    bcnt[i] = 0;                       // 256 entries (>= NB)
    if (i == 0) rowstart[N_NODES] = N_EDGES;
}

// ---------------- coarse bucket histogram (per-block LDS, few global atomics) ----------------
__global__ __launch_bounds__(256) void k_bcount(const int* __restrict__ dst,
                                                int* __restrict__ bcnt) {
    __shared__ int hist[256];
    int tid = threadIdx.x;
    hist[tid] = 0;
    __syncthreads();
    int e0 = blockIdx.x * EPB1;
    int n  = min(EPB1, N_EDGES - e0);
    for (int k = tid; k < n; k += 256)
        atomicAdd(&hist[dst[e0 + k] >> BSH], 1);
    __syncthreads();
    int c = hist[tid];
    if (c) atomicAdd(&bcnt[tid], c);
}

// ---------------- scan 196 bucket counts -> bstart, init global cursors ----------------
__global__ __launch_bounds__(256) void k_bscan(const int* __restrict__ bcnt,
                                               int* __restrict__ bstart,
                                               int* __restrict__ bcur) {
    __shared__ int s[256];
    int tid = threadIdx.x;
    int c = bcnt[tid];
    s[tid] = c;
    __syncthreads();
    for (int off = 1; off < 256; off <<= 1) {
        int t = (tid >= off) ? s[tid - off] : 0;
        __syncthreads();
        s[tid] += t;
        __syncthreads();
    }
    if (tid == 0) bstart[0] = 0;
    bstart[tid + 1] = s[tid];          // inclusive -> bstart[b+1]
    bcur[tid]       = s[tid] - c;      // exclusive base, running cursor
}

// ---------------- bucket scatter: block reserves contiguous runs (coalesced writes) ----------
__global__ __launch_bounds__(256) void k_bscatter(const int* __restrict__ src,
                                                  const int* __restrict__ dst,
                                                  int* __restrict__ bcur,
                                                  unsigned int* __restrict__ ebuf) {
    __shared__ unsigned int pk[EPB2];
    __shared__ unsigned short bb[EPB2];
    __shared__ int hist[256], base[256], lcur[256];
    int tid = threadIdx.x;
    hist[tid] = 0; lcur[tid] = 0;
    __syncthreads();
    int e0 = blockIdx.x * EPB2;
    int n  = min(EPB2, N_EDGES - e0);
    for (int k = tid; k < n; k += 256) {
        int d = dst[e0 + k];
        int b = d >> BSH;
        pk[k] = ((unsigned int)src[e0 + k] << BSH) | (unsigned int)(d & (BNODES - 1));
        bb[k] = (unsigned short)b;
        atomicAdd(&hist[b], 1);
    }
    __syncthreads();
    int h = hist[tid];
    base[tid] = h ? atomicAdd(&bcur[tid], h) : 0;   // one global atomic per touched bucket
    __syncthreads();
    for (int k = tid; k < n; k += 256) {
        int b = bb[k];
        int pos = atomicAdd(&lcur[b], 1);
        ebuf[base[b] + pos] = pk[k];                // block-private run -> L2 write-combine
    }
}

// ---------------- per-bucket LDS counting sort: csr_src + rowstart + dinv ----------------
__global__ __launch_bounds__(512) void k_bsort(const int* __restrict__ bstart,
                                               const unsigned int* __restrict__ ebuf,
                                               int* __restrict__ rowstart,
                                               float* __restrict__ dinv,
                                               int* __restrict__ csr_src) {
    __shared__ int hist[512], cur[512];
    int tid = threadIdx.x;
    int b   = blockIdx.x;
    int e0 = bstart[b], e1 = bstart[b + 1];
    hist[tid] = 0;
    __syncthreads();
    for (int i = e0 + tid; i < e1; i += 512)
        atomicAdd(&hist[ebuf[i] & (BNODES - 1)], 1);
    __syncthreads();
    int deg = hist[tid];
    for (int off = 1; off < 512; off <<= 1) {       // inclusive Hillis-Steele
        int t = (tid >= off) ? hist[tid - off] : 0;
        __syncthreads();
        hist[tid] += t;
        __syncthreads();
    }
    int excl = hist[tid] - deg;
    int node = (b << BSH) + tid;
    if (node < N_NODES) {
        rowstart[node] = e0 + excl;
        dinv[node]     = rsqrtf((float)(deg + 1)); // +1 self-loop
    }
    cur[tid] = excl;
    __syncthreads();
    for (int i = e0 + tid; i < e1; i += 512) {
        unsigned int p = ebuf[i];
        int pos = atomicAdd(&cur[p & (BNODES - 1)], 1);
        csr_src[e0 + pos] = (int)(p >> BSH);        // block-private region
    }
}

// ---------------- layer-1 GEMM: h1s = (x @ W1) * dinv ----------------
// One wave per node; W1 fragment in registers; value-halving butterfly reduction.
// 2-deep row prefetch: load for node i+2 is issued during compute of node i,
// giving ~2 iterations (>HBM latency) of issue-to-use distance.
__global__ __launch_bounds__(256, 2) void k_gemm1(
    const float* __restrict__ x, const float* __restrict__ W1,
    const float* __restrict__ dinv, float* __restrict__ h1s) {
    const int tid = threadIdx.x;
    const int l   = tid & 63;
    const int wid = blockIdx.x * 4 + (tid >> 6);
    const int nw  = GEMM1_BLOCKS * 4;

    float w[8][16];
#pragma unroll
    for (int q = 0; q < 4; ++q) {
#pragma unroll
        for (int c = 0; c < 4; ++c) {
            float4 t0 = *(const float4*)(W1 + (size_t)(4 * l + q) * 16 + 4 * c);
            w[q][4*c+0] = t0.x; w[q][4*c+1] = t0.y; w[q][4*c+2] = t0.z; w[q][4*c+3] = t0.w;
            float4 t1 = *(const float4*)(W1 + (size_t)(256 + 4 * l + q) * 16 + 4 * c);
            w[4+q][4*c+0] = t1.x; w[4+q][4*c+1] = t1.y; w[4+q][4*c+2] = t1.z; w[4+q][4*c+3] = t1.w;
        }
    }

    const int b0 = l & 1, b1 = (l >> 1) & 1, b2 = (l >> 2) & 1, b3 = (l >> 3) & 1;

    int n = wid;
    if (n >= N_NODES) return;
    const float* xr = x + (size_t)n * IN_DIM;
    float4 v0 = *(const float4*)(xr + 4 * l);
    float4 v1 = *(const float4*)(xr + 256 + 4 * l);

    int n1 = n + nw;
    float4 u0, u1;
    {
        int np = (n1 < N_NODES) ? n1 : n;
        const float* xp = x + (size_t)np * IN_DIM;
        u0 = *(const float4*)(xp + 4 * l);
        u1 = *(const float4*)(xp + 256 + 4 * l);
    }

    for (;;) {
        // prefetch node n+2*nw (clamped; harmless cached re-read near the tail)
        int n2 = n1 + nw;
        int np = (n2 < N_NODES) ? n2 : n;
        const float* xp = x + (size_t)np * IN_DIM;
        float4 pf0 = *(const float4*)(xp + 4 * l);
        float4 pf1 = *(const float4*)(xp + 256 + 4 * l);

        float di = dinv[n];

        float p[16];
#pragma unroll
        for (int j = 0; j < 16; ++j) {
            float a = v0.x * w[0][j];
            a = fmaf(v0.y, w[1][j], a);
            a = fmaf(v0.z, w[2][j], a);
            a = fmaf(v0.w, w[3][j], a);
            a = fmaf(v1.x, w[4][j], a);
            a = fmaf(v1.y, w[5][j], a);
            a = fmaf(v1.z, w[6][j], a);
            a = fmaf(v1.w, w[7][j], a);
            p[j] = a;
        }

        float q8[8];
#pragma unroll
        for (int m = 0; m < 8; ++m) {
            float keep = b0 ? p[2*m+1] : p[2*m];
            float give = b0 ? p[2*m]   : p[2*m+1];
            q8[m] = keep + __shfl_xor(give, 1);
        }
        float r4[4];
#pragma unroll
        for (int t = 0; t < 4; ++t) {
            float keep = b1 ? q8[2*t+1] : q8[2*t];
            float give = b1 ? q8[2*t]   : q8[2*t+1];
            r4[t] = keep + __shfl_xor(give, 2);
        }
        float s2[2];
#pragma unroll
        for (int u = 0; u < 2; ++u) {
            float keep = b2 ? r4[2*u+1] : r4[2*u];
            float give = b2 ? r4[2*u]   : r4[2*u+1];
            s2[u] = keep + __shfl_xor(give, 4);
        }
        float t0 = (b3 ? s2[1] : s2[0]) + __shfl_xor(b3 ? s2[0] : s2[1], 8);
        t0 += __shfl_xor(t0, 16);
        t0 += __shfl_xor(t0, 32);

        if (l < 16) h1s[(size_t)n * 16 + l] = t0 * di;

        if (n1 >= N_NODES) break;
        n = n1; n1 = n2;
        v0 = u0; v1 = u1;
        u0 = pf0; u1 = pf1;
    }
}

// ---------------- layer-1 gather-aggregate + bias + relu + layer-2 GEMM fused ----------
// 16 threads per node; register accumulate; after relu, lane j holds z_j and the
// 16-lane group computes h2 via shuffles (replaces the separate k_layer2 kernel).
__global__ __launch_bounds__(256) void k_agg1(
    const int* __restrict__ rowstart, const int* __restrict__ csr_src,
    const float* __restrict__ h1s, const float* __restrict__ dinv,
    const float* __restrict__ b1, const float* __restrict__ W2,
    float* __restrict__ h2s) {
    int gid = blockIdx.x * 256 + threadIdx.x;
    int g = gid >> 4, j = gid & 15;
    bool valid = g < N_NODES;
    int n = valid ? g : (N_NODES - 1);

    // W2 column for this lane's output class (lanes 7..15 inactive on store)
    float w2k[16];
#pragma unroll
    for (int k = 0; k < 16; ++k) w2k[k] = (j < 7) ? W2[k * 7 + j] : 0.f;

    int start = rowstart[n], end = rowstart[n + 1];
    float acc = h1s[(size_t)n * 16 + j];   // self-loop term
    int i = start;
    for (; i + 8 <= end; i += 8) {
        int s[8];
#pragma unroll
        for (int u = 0; u < 8; ++u) s[u] = csr_src[i + u];
        float v[8];
#pragma unroll
        for (int u = 0; u < 8; ++u) v[u] = h1s[(size_t)s[u] * 16 + j];  // 8 gathers in flight
        acc += ((v[0] + v[1]) + (v[2] + v[3])) + ((v[4] + v[5]) + (v[6] + v[7]));
    }
    for (; i < end; ++i)
        acc += h1s[(size_t)csr_src[i] * 16 + j];

    float di = dinv[n];
    float zj = fmaxf(di * acc + b1[j], 0.f);

    // h2 = (z @ W2) * di via intra-group shuffles
    float o = 0.f;
#pragma unroll
    for (int k = 0; k < 16; ++k) {
        float zk = __shfl(zj, k, 16);
        o = fmaf(zk, w2k[k], o);
    }
    if (valid && j < 8) h2s[(size_t)n * 8 + j] = (j < 7) ? o * di : 0.f;
}

// ---------------- layer-2 gather-aggregate + bias + log_softmax ----------------
// 8 threads per node; register accumulate; explicit 8-edge batches for MLP.
__global__ __launch_bounds__(256) void k_agg2(
    const int* __restrict__ rowstart, const int* __restrict__ csr_src,
    const float* __restrict__ h2s, const float* __restrict__ dinv,
    const float* __restrict__ b2, float* __restrict__ out) {
    int gid = blockIdx.x * 256 + threadIdx.x;
    int g = gid >> 3, j = gid & 7;
    bool valid = g < N_NODES;
    int n = valid ? g : (N_NODES - 1);
    int start = rowstart[n], end = rowstart[n + 1];
    float acc = h2s[(size_t)n * 8 + j];    // self-loop term (slot 7 reads 0)
    int i = start;
    for (; i + 8 <= end; i += 8) {
        int s[8];
#pragma unroll
        for (int u = 0; u < 8; ++u) s[u] = csr_src[i + u];
        float v[8];
#pragma unroll
        for (int u = 0; u < 8; ++u) v[u] = h2s[(size_t)s[u] * 8 + j];   // 8 gathers in flight
        acc += ((v[0] + v[1]) + (v[2] + v[3])) + ((v[4] + v[5]) + (v[6] + v[7]));
    }
    for (; i < end; ++i)
        acc += h2s[(size_t)csr_src[i] * 8 + j];
    float v = dinv[n] * acc + ((j < 7) ? b2[j] : -1e30f);
    float m = v;
    m = fmaxf(m, __shfl_xor(m, 1));
    m = fmaxf(m, __shfl_xor(m, 2));
    m = fmaxf(m, __shfl_xor(m, 4));
    float e = (j < 7) ? expf(v - m) : 0.f;
    float ssum = e;
    ssum += __shfl_xor(ssum, 1);
    ssum += __shfl_xor(ssum, 2);
    ssum += __shfl_xor(ssum, 4);
    float ls = logf(ssum) + m;
    if (valid && j < 7) out[(size_t)n * 7 + j] = v - ls;
}

extern "C" void kernel_launch(void* const* d_in, const int* in_sizes, int n_in,
                              void* d_out, int out_size, void* d_ws, size_t ws_size,
                              hipStream_t stream) {
    const float* x  = (const float*)d_in[0];
    const int*   ei = (const int*)d_in[1];
    const float* W1 = (const float*)d_in[2];
    const float* b1 = (const float*)d_in[3];
    const float* W2 = (const float*)d_in[4];
    const float* b2 = (const float*)d_in[5];
    float* out = (float*)d_out;

    const int* src = ei;             // edge_index[0]
    const int* dst = ei + N_EDGES;   // edge_index[1]

    char* ws = (char*)d_ws;
    size_t o = 0;
    auto alloc = [&](size_t bytes) -> void* {
        void* p = ws + o;
        o = (o + bytes + 255) & ~(size_t)255;
        return p;
    };
    int*   bcnt     = (int*)alloc(256 * 4);
    int*   bstart   = (int*)alloc(257 * 4);
    int*   bcur     = (int*)alloc(256 * 4);
    int*   rowstart = (int*)alloc(((size_t)N_NODES + 1) * 4);
    float* dinv     = (float*)alloc((size_t)N_NODES * 4);
    int*   csr_src  = (int*)alloc((size_t)N_EDGES * 4);
    // union: ebuf (dead after k_bsort) overlaps h1s (live after k_bsort)
    char*  uni      = (char*)alloc((size_t)N_EDGES * 4);   // 12.8MB >= h1s 6.4MB
    unsigned int* ebuf = (unsigned int*)uni;
    float* h1s      = (float*)uni;
    float* h2s      = (float*)alloc((size_t)N_NODES * 8 * 4);

    k_zero    <<<1, 256, 0, stream>>>(bcnt, rowstart);
    k_bcount  <<<NBLK1, 256, 0, stream>>>(dst, bcnt);
    k_bscan   <<<1, 256, 0, stream>>>(bcnt, bstart, bcur);
    k_bscatter<<<NBLK2, 256, 0, stream>>>(src, dst, bcur, ebuf);
    k_bsort   <<<NB, 512, 0, stream>>>(bstart, ebuf, rowstart, dinv, csr_src);
    k_gemm1   <<<GEMM1_BLOCKS, 256, 0, stream>>>(x, W1, dinv, h1s);
    k_agg1    <<<(N_NODES * 16 + 255) / 256, 256, 0, stream>>>(rowstart, csr_src, h1s, dinv, b1, W2, h2s);
    k_agg2    <<<(N_NODES * 8 + 255) / 256, 256, 0, stream>>>(rowstart, csr_src, h2s, dinv, b2, out);
}

// Round 11
// 452.114 us; speedup vs baseline: 1.9750x; 1.0100x over previous
//
#include <hip/hip_runtime.h>
#include <hip/hip_fp16.h>

#define N_NODES 100000
#define N_EDGES 3200000
#define IN_DIM  512
#define HIDDEN  16
#define NCLS    7

#define BSH     9
#define BNODES  512                                  // nodes per bucket
#define NB      ((N_NODES + BNODES - 1) / BNODES)    // 196 buckets

#define EPB1    8192                                 // edges/block, k_bcount
#define NBLK1   ((N_EDGES + EPB1 - 1) / EPB1)        // 391
#define EPB2    4096                                 // edges/block, k_bscatter
#define NBLK2   ((N_EDGES + EPB2 - 1) / EPB2)        // 782

#define GEMM1_BLOCKS 512                             // 2048 waves

// ---------------- init ----------------
__global__ void k_zero(int* __restrict__ bcnt, int* __restrict__ rowstart) {
    int i = threadIdx.x;
    bcnt[i] = 0;                       // 256 entries (>= NB)
    if (i == 0) rowstart[N_NODES] = N_EDGES;
}

// ---------------- coarse bucket histogram (per-block LDS, few global atomics) ----------------
__global__ __launch_bounds__(256) void k_bcount(const int* __restrict__ dst,
                                                int* __restrict__ bcnt) {
    __shared__ int hist[256];
    int tid = threadIdx.x;
    hist[tid] = 0;
    __syncthreads();
    int e0 = blockIdx.x * EPB1;
    int n  = min(EPB1, N_EDGES - e0);
    for (int k = tid; k < n; k += 256)
        atomicAdd(&hist[dst[e0 + k] >> BSH], 1);
    __syncthreads();
    int c = hist[tid];
    if (c) atomicAdd(&bcnt[tid], c);
}

// ---------------- scan 196 bucket counts -> bstart, init global cursors ----------------
__global__ __launch_bounds__(256) void k_bscan(const int* __restrict__ bcnt,
                                               int* __restrict__ bstart,
                                               int* __restrict__ bcur) {
    __shared__ int s[256];
    int tid = threadIdx.x;
    int c = bcnt[tid];
    s[tid] = c;
    __syncthreads();
    for (int off = 1; off < 256; off <<= 1) {
        int t = (tid >= off) ? s[tid - off] : 0;
        __syncthreads();
        s[tid] += t;
        __syncthreads();
    }
    if (tid == 0) bstart[0] = 0;
    bstart[tid + 1] = s[tid];          // inclusive -> bstart[b+1]
    bcur[tid]       = s[tid] - c;      // exclusive base, running cursor
}

// ---------------- bucket scatter: block reserves contiguous runs (coalesced writes) ----------
__global__ __launch_bounds__(256) void k_bscatter(const int* __restrict__ src,
                                                  const int* __restrict__ dst,
                                                  int* __restrict__ bcur,
                                                  unsigned int* __restrict__ ebuf) {
    __shared__ unsigned int pk[EPB2];
    __shared__ unsigned short bb[EPB2];
    __shared__ int hist[256], base[256], lcur[256];
    int tid = threadIdx.x;
    hist[tid] = 0; lcur[tid] = 0;
    __syncthreads();
    int e0 = blockIdx.x * EPB2;
    int n  = min(EPB2, N_EDGES - e0);
    for (int k = tid; k < n; k += 256) {
        int d = dst[e0 + k];
        int b = d >> BSH;
        pk[k] = ((unsigned int)src[e0 + k] << BSH) | (unsigned int)(d & (BNODES - 1));
        bb[k] = (unsigned short)b;
        atomicAdd(&hist[b], 1);
    }
    __syncthreads();
    int h = hist[tid];
    base[tid] = h ? atomicAdd(&bcur[tid], h) : 0;   // one global atomic per touched bucket
    __syncthreads();
    for (int k = tid; k < n; k += 256) {
        int b = bb[k];
        int pos = atomicAdd(&lcur[b], 1);
        ebuf[base[b] + pos] = pk[k];                // block-private run -> L2 write-combine
    }
}

// ---------------- per-bucket LDS counting sort: csr_src + rowstart + dinv ----------------
__global__ __launch_bounds__(512) void k_bsort(const int* __restrict__ bstart,
                                               const unsigned int* __restrict__ ebuf,
                                               int* __restrict__ rowstart,
                                               float* __restrict__ dinv,
                                               int* __restrict__ csr_src) {
    __shared__ int hist[512], cur[512];
    int tid = threadIdx.x;
    int b   = blockIdx.x;
    int e0 = bstart[b], e1 = bstart[b + 1];
    hist[tid] = 0;
    __syncthreads();
    for (int i = e0 + tid; i < e1; i += 512)
        atomicAdd(&hist[ebuf[i] & (BNODES - 1)], 1);
    __syncthreads();
    int deg = hist[tid];
    for (int off = 1; off < 512; off <<= 1) {       // inclusive Hillis-Steele
        int t = (tid >= off) ? hist[tid - off] : 0;
        __syncthreads();
        hist[tid] += t;
        __syncthreads();
    }
    int excl = hist[tid] - deg;
    int node = (b << BSH) + tid;
    if (node < N_NODES) {
        rowstart[node] = e0 + excl;
        dinv[node]     = rsqrtf((float)(deg + 1)); // +1 self-loop
    }
    cur[tid] = excl;
    __syncthreads();
    for (int i = e0 + tid; i < e1; i += 512) {
        unsigned int p = ebuf[i];
        int pos = atomicAdd(&cur[p & (BNODES - 1)], 1);
        csr_src[e0 + pos] = (int)(p >> BSH);        // block-private region
    }
}

// ---------------- layer-1 GEMM: h1h = fp16((x @ W1) * dinv) ----------------
// One wave per node; W1 fragment in registers; value-halving butterfly reduction.
// h1 stored as fp16: 3.2MB total -> fits in every XCD's 4MB L2 for the gather phase.
__global__ __launch_bounds__(256, 2) void k_gemm1(
    const float* __restrict__ x, const float* __restrict__ W1,
    const float* __restrict__ dinv, __half* __restrict__ h1h) {
    const int tid = threadIdx.x;
    const int l   = tid & 63;
    const int wid = blockIdx.x * 4 + (tid >> 6);
    const int nw  = GEMM1_BLOCKS * 4;

    float w[8][16];
#pragma unroll
    for (int q = 0; q < 4; ++q) {
#pragma unroll
        for (int c = 0; c < 4; ++c) {
            float4 t0 = *(const float4*)(W1 + (size_t)(4 * l + q) * 16 + 4 * c);
            w[q][4*c+0] = t0.x; w[q][4*c+1] = t0.y; w[q][4*c+2] = t0.z; w[q][4*c+3] = t0.w;
            float4 t1 = *(const float4*)(W1 + (size_t)(256 + 4 * l + q) * 16 + 4 * c);
            w[4+q][4*c+0] = t1.x; w[4+q][4*c+1] = t1.y; w[4+q][4*c+2] = t1.z; w[4+q][4*c+3] = t1.w;
        }
    }

    const int b0 = l & 1, b1 = (l >> 1) & 1, b2 = (l >> 2) & 1, b3 = (l >> 3) & 1;

    int n = wid;
    if (n >= N_NODES) return;
    const float* xr = x + (size_t)n * IN_DIM;
    float4 v0 = *(const float4*)(xr + 4 * l);
    float4 v1 = *(const float4*)(xr + 256 + 4 * l);

    int n1 = n + nw;
    float4 u0, u1;
    {
        int np = (n1 < N_NODES) ? n1 : n;
        const float* xp = x + (size_t)np * IN_DIM;
        u0 = *(const float4*)(xp + 4 * l);
        u1 = *(const float4*)(xp + 256 + 4 * l);
    }

    for (;;) {
        int n2 = n1 + nw;
        int np = (n2 < N_NODES) ? n2 : n;
        const float* xp = x + (size_t)np * IN_DIM;
        float4 pf0 = *(const float4*)(xp + 4 * l);
        float4 pf1 = *(const float4*)(xp + 256 + 4 * l);

        float di = dinv[n];

        float p[16];
#pragma unroll
        for (int j = 0; j < 16; ++j) {
            float a = v0.x * w[0][j];
            a = fmaf(v0.y, w[1][j], a);
            a = fmaf(v0.z, w[2][j], a);
            a = fmaf(v0.w, w[3][j], a);
            a = fmaf(v1.x, w[4][j], a);
            a = fmaf(v1.y, w[5][j], a);
            a = fmaf(v1.z, w[6][j], a);
            a = fmaf(v1.w, w[7][j], a);
            p[j] = a;
        }

        float q8[8];
#pragma unroll
        for (int m = 0; m < 8; ++m) {
            float keep = b0 ? p[2*m+1] : p[2*m];
            float give = b0 ? p[2*m]   : p[2*m+1];
            q8[m] = keep + __shfl_xor(give, 1);
        }
        float r4[4];
#pragma unroll
        for (int t = 0; t < 4; ++t) {
            float keep = b1 ? q8[2*t+1] : q8[2*t];
            float give = b1 ? q8[2*t]   : q8[2*t+1];
            r4[t] = keep + __shfl_xor(give, 2);
        }
        float s2[2];
#pragma unroll
        for (int u = 0; u < 2; ++u) {
            float keep = b2 ? r4[2*u+1] : r4[2*u];
            float give = b2 ? r4[2*u]   : r4[2*u+1];
            s2[u] = keep + __shfl_xor(give, 4);
        }
        float t0 = (b3 ? s2[1] : s2[0]) + __shfl_xor(b3 ? s2[0] : s2[1], 8);
        t0 += __shfl_xor(t0, 16);
        t0 += __shfl_xor(t0, 32);

        if (l < 16) h1h[(size_t)n * 16 + l] = __float2half(t0 * di);

        if (n1 >= N_NODES) break;
        n = n1; n1 = n2;
        v0 = u0; v1 = u1;
        u0 = pf0; u1 = pf1;
    }
}

// ---------------- layer-1 gather-aggregate + bias + relu + layer-2 GEMM fused ----------
// 16 threads per node; register accumulate over fp16 h1 gathers (32B per group);
// after relu, lane j holds z_j; 16-lane shuffles compute h2 (fp32).
__global__ __launch_bounds__(256) void k_agg1(
    const int* __restrict__ rowstart, const int* __restrict__ csr_src,
    const __half* __restrict__ h1h, const float* __restrict__ dinv,
    const float* __restrict__ b1, const float* __restrict__ W2,
    float* __restrict__ h2s) {
    int gid = blockIdx.x * 256 + threadIdx.x;
    int g = gid >> 4, j = gid & 15;
    bool valid = g < N_NODES;
    int n = valid ? g : (N_NODES - 1);

    float w2k[16];
#pragma unroll
    for (int k = 0; k < 16; ++k) w2k[k] = (j < 7) ? W2[k * 7 + j] : 0.f;

    int start = rowstart[n], end = rowstart[n + 1];
    float acc = __half2float(h1h[(size_t)n * 16 + j]);   // self-loop term
    int i = start;
    for (; i + 8 <= end; i += 8) {
        int s[8];
#pragma unroll
        for (int u = 0; u < 8; ++u) s[u] = csr_src[i + u];
        float v[8];
#pragma unroll
        for (int u = 0; u < 8; ++u) v[u] = __half2float(h1h[(size_t)s[u] * 16 + j]);  // 8 gathers in flight
        acc += ((v[0] + v[1]) + (v[2] + v[3])) + ((v[4] + v[5]) + (v[6] + v[7]));
    }
    for (; i < end; ++i)
        acc += __half2float(h1h[(size_t)csr_src[i] * 16 + j]);

    float di = dinv[n];
    float zj = fmaxf(di * acc + b1[j], 0.f);

    float o = 0.f;
#pragma unroll
    for (int k = 0; k < 16; ++k) {
        float zk = __shfl(zj, k, 16);
        o = fmaf(zk, w2k[k], o);
    }
    if (valid && j < 8) h2s[(size_t)n * 8 + j] = (j < 7) ? o * di : 0.f;
}

// ---------------- layer-2 gather-aggregate + bias + log_softmax ----------------
// 8 threads per node; register accumulate; explicit 8-edge batches for MLP.
__global__ __launch_bounds__(256) void k_agg2(
    const int* __restrict__ rowstart, const int* __restrict__ csr_src,
    const float* __restrict__ h2s, const float* __restrict__ dinv,
    const float* __restrict__ b2, float* __restrict__ out) {
    int gid = blockIdx.x * 256 + threadIdx.x;
    int g = gid >> 3, j = gid & 7;
    bool valid = g < N_NODES;
    int n = valid ? g : (N_NODES - 1);
    int start = rowstart[n], end = rowstart[n + 1];
    float acc = h2s[(size_t)n * 8 + j];    // self-loop term (slot 7 reads 0)
    int i = start;
    for (; i + 8 <= end; i += 8) {
        int s[8];
#pragma unroll
        for (int u = 0; u < 8; ++u) s[u] = csr_src[i + u];
        float v[8];
#pragma unroll
        for (int u = 0; u < 8; ++u) v[u] = h2s[(size_t)s[u] * 8 + j];   // 8 gathers in flight
        acc += ((v[0] + v[1]) + (v[2] + v[3])) + ((v[4] + v[5]) + (v[6] + v[7]));
    }
    for (; i < end; ++i)
        acc += h2s[(size_t)csr_src[i] * 8 + j];
    float v = dinv[n] * acc + ((j < 7) ? b2[j] : -1e30f);
    float m = v;
    m = fmaxf(m, __shfl_xor(m, 1));
    m = fmaxf(m, __shfl_xor(m, 2));
    m = fmaxf(m, __shfl_xor(m, 4));
    float e = (j < 7) ? expf(v - m) : 0.f;
    float ssum = e;
    ssum += __shfl_xor(ssum, 1);
    ssum += __shfl_xor(ssum, 2);
    ssum += __shfl_xor(ssum, 4);
    float ls = logf(ssum) + m;
    if (valid && j < 7) out[(size_t)n * 7 + j] = v - ls;
}

extern "C" void kernel_launch(void* const* d_in, const int* in_sizes, int n_in,
                              void* d_out, int out_size, void* d_ws, size_t ws_size,
                              hipStream_t stream) {
    const float* x  = (const float*)d_in[0];
    const int*   ei = (const int*)d_in[1];
    const float* W1 = (const float*)d_in[2];
    const float* b1 = (const float*)d_in[3];
    const float* W2 = (const float*)d_in[4];
    const float* b2 = (const float*)d_in[5];
    float* out = (float*)d_out;

    const int* src = ei;             // edge_index[0]
    const int* dst = ei + N_EDGES;   // edge_index[1]

    char* ws = (char*)d_ws;
    size_t o = 0;
    auto alloc = [&](size_t bytes) -> void* {
        void* p = ws + o;
        o = (o + bytes + 255) & ~(size_t)255;
        return p;
    };
    int*   bcnt     = (int*)alloc(256 * 4);
    int*   bstart   = (int*)alloc(257 * 4);
    int*   bcur     = (int*)alloc(256 * 4);
    int*   rowstart = (int*)alloc(((size_t)N_NODES + 1) * 4);
    float* dinv     = (float*)alloc((size_t)N_NODES * 4);
    int*   csr_src  = (int*)alloc((size_t)N_EDGES * 4);
    // union: ebuf (dead after k_bsort) overlaps h1h (live after k_bsort)
    char*  uni      = (char*)alloc((size_t)N_EDGES * 4);   // 12.8MB >= h1h 3.2MB
    unsigned int* ebuf = (unsigned int*)uni;
    __half* h1h     = (__half*)uni;
    float* h2s      = (float*)alloc((size_t)N_NODES * 8 * 4);

    k_zero    <<<1, 256, 0, stream>>>(bcnt, rowstart);
    k_bcount  <<<NBLK1, 256, 0, stream>>>(dst, bcnt);
    k_bscan   <<<1, 256, 0, stream>>>(bcnt, bstart, bcur);
    k_bscatter<<<NBLK2, 256, 0, stream>>>(src, dst, bcur, ebuf);
    k_bsort   <<<NB, 512, 0, stream>>>(bstart, ebuf, rowstart, dinv, csr_src);
    k_gemm1   <<<GEMM1_BLOCKS, 256, 0, stream>>>(x, W1, dinv, h1h);
    k_agg1    <<<(N_NODES * 16 + 255) / 256, 256, 0, stream>>>(rowstart, csr_src, h1h, dinv, b1, W2, h2s);
    k_agg2    <<<(N_NODES * 8 + 255) / 256, 256, 0, stream>>>(rowstart, csr_src, h2s, dinv, b2, out);
}